// Round 1
// baseline (47.716 us; speedup 1.0000x reference)
//
#include <hip/hip_runtime.h>

#define CW 48
#define HR 3
#define VR 3
#define BB 2
#define CC 16
#define HH 128
#define WW 256
#define TH 16                 // output rows per block
#define NROWS (TH + 2*VR)     // 22 ssd_raw rows staged
#define NX (WW + 2*HR)        // 262 ssd_raw cols (x = -3 .. 258)
#define NXP 264               // padded LDS stride

__global__ __launch_bounds__(256) void ssd_cost_kernel(
    const float* __restrict__ Lg, const float* __restrict__ Rg,
    float* __restrict__ out)
{
    // grid: b * CW * (HH/TH) blocks
    const int nrg = HH / TH;
    int bid = blockIdx.x;
    int rg  = bid % nrg;
    int d   = (bid / nrg) % CW;
    int b   = bid / (nrg * CW);
    int h0  = rg * TH;
    int tid = threadIdx.x;

    __shared__ float ssd[NROWS][NXP];
    __shared__ float cs[TH][NXP];

    const float* Lb = Lg + (size_t)b * CC * HH * WW;
    const float* Rb = Rg + (size_t)b * CC * HH * WW;

    // ---- phase 1: ssd_raw(y, x) for this block's fixed d ----
    for (int pos = tid; pos < NROWS * NX; pos += 256) {
        int row = pos / NX;
        int xi  = pos - row * NX;
        int y = h0 - VR + row;
        int x = xi - HR;
        float acc = 0.f;
        if (y >= 0 && y < HH) {
            int xl = x + d;
            bool lin = (xl >= 0 && xl < WW);
            bool rin = (x  >= 0 && x  < WW);
            const float* lp = Lb + (size_t)y * WW + xl;
            const float* rp = Rb + (size_t)y * WW + x;
            #pragma unroll
            for (int c = 0; c < CC; ++c) {
                float lv = lin ? lp[(size_t)c * HH * WW] : 0.f;
                float rv = rin ? rp[(size_t)c * HH * WW] : 0.f;
                float df = lv - rv;
                acc = fmaf(df, df, acc);
            }
        }
        ssd[row][xi] = acc;
    }
    __syncthreads();

    // ---- phase 2a: vertical 7-tap box ----
    for (int pos = tid; pos < TH * NX; pos += 256) {
        int r  = pos / NX;
        int xi = pos - r * NX;
        float s = 0.f;
        #pragma unroll
        for (int j = 0; j < 2*VR + 1; ++j) s += ssd[r + j][xi];
        cs[r][xi] = s;
    }
    __syncthreads();

    // ---- phase 2b: horizontal 7-tap box + store ----
    for (int pos = tid; pos < TH * WW; pos += 256) {
        int r = pos >> 8;          // WW == 256
        int w = pos & (WW - 1);
        float s = 0.f;
        #pragma unroll
        for (int j = 0; j < 2*HR + 1; ++j) s += cs[r][w + j];
        out[(((size_t)b * HH + (h0 + r)) * WW + w) * CW + d] = s;
    }
}

extern "C" void kernel_launch(void* const* d_in, const int* in_sizes, int n_in,
                              void* d_out, int out_size, void* d_ws, size_t ws_size,
                              hipStream_t stream) {
    const float* L = (const float*)d_in[0];
    const float* R = (const float*)d_in[1];
    float* out = (float*)d_out;
    dim3 grid(BB * CW * (HH / TH));
    ssd_cost_kernel<<<grid, 256, 0, stream>>>(L, R, out);
}

// Round 2
// 45.616 us; speedup vs baseline: 1.0460x; 1.0460x over previous
//
#include <hip/hip_runtime.h>

#define CW 48
#define HR 3
#define VR 3
#define BB 2
#define CC 16
#define HH 128
#define WW 256

#define YROWS (HH + 2*VR)        // 134 ssd rows (y = -3 .. 130)
#define DQ 12                    // disparities per block in kernel A
#define NXI 262                  // x = -3 .. 258  (xi = x+3)
#define LW 312                   // L LDS stride (col = x+d, idx = col+3, max 308)
#define RW 264                   // R LDS stride
#define SW 264                   // ssd row stride

// ---------------- Kernel A: per-row SSD + horizontal 7-tap ----------------
// grid: BB * YROWS * 4  blocks; Hws layout [b][yi][d][w] (w contiguous)
__global__ __launch_bounds__(256) void ssd_hraw_kernel(
    const float* __restrict__ Lg, const float* __restrict__ Rg,
    float* __restrict__ Hws)
{
    int bid = blockIdx.x;
    int dq  = bid & 3;
    int yi  = (bid >> 2) % YROWS;
    int b   = bid / (4 * YROWS);
    int d0  = dq * DQ;
    int y   = yi - VR;
    int tid = threadIdx.x;

    float* Hrow = Hws + (((size_t)b * YROWS + yi) * CW + d0) * WW;

    if (y < 0 || y >= HH) {
        // ssd rows outside the image are all-zero (both images zero-padded)
        for (int i = tid; i < DQ * WW; i += 256) Hrow[i] = 0.f;
        return;
    }

    __shared__ float Lsh[CC * LW];
    __shared__ float Rsh[CC * RW];
    __shared__ float Ssh[DQ * SW];

    // zero-extend borders (zero everything, then fill valid cols)
    for (int i = tid; i < CC * LW; i += 256) Lsh[i] = 0.f;
    for (int i = tid; i < CC * RW; i += 256) Rsh[i] = 0.f;
    __syncthreads();

    const float* Lb = Lg + (size_t)b * CC * HH * WW + (size_t)y * WW;
    const float* Rb = Rg + (size_t)b * CC * HH * WW + (size_t)y * WW;
    #pragma unroll
    for (int c = 0; c < CC; ++c) {
        Lsh[c * LW + HR + tid] = Lb[(size_t)c * HH * WW + tid];  // col = tid
        Rsh[c * RW + HR + tid] = Rb[(size_t)c * HH * WW + tid];
    }
    __syncthreads();

    // ssd_raw(y, x, d) for x = xi-3, d = d0..d0+11; all reads from LDS
    for (int xi = tid; xi < NXI; xi += 256) {
        float acc[DQ];
        #pragma unroll
        for (int dd = 0; dd < DQ; ++dd) acc[dd] = 0.f;
        #pragma unroll
        for (int c = 0; c < CC; ++c) {
            float rc = Rsh[c * RW + xi];
            const float* lp = &Lsh[c * LW + xi + d0];  // idx = (x+d)+3
            #pragma unroll
            for (int dd = 0; dd < DQ; ++dd) {
                float df = lp[dd] - rc;
                acc[dd] = fmaf(df, df, acc[dd]);
            }
        }
        #pragma unroll
        for (int dd = 0; dd < DQ; ++dd) Ssh[dd * SW + xi] = acc[dd];
    }
    __syncthreads();

    // horizontal 7-tap: Hws(y,w,d) = sum_{j=0..6} ssd[d][w+j]
    {
        int w = tid;
        #pragma unroll
        for (int dd = 0; dd < DQ; ++dd) {
            float s = 0.f;
            #pragma unroll
            for (int j = 0; j < 2*HR + 1; ++j) s += Ssh[dd * SW + w + j];
            Hrow[dd * WW + w] = s;   // coalesced in w
        }
    }
}

// ---------------- Kernel B: vertical 7-tap + transpose-store ----------------
// grid: BB * HH * 3 blocks, 16 d's per block
__global__ __launch_bounds__(256) void vsum_store_kernel(
    const float* __restrict__ Hws, float* __restrict__ out)
{
    int bid = blockIdx.x;
    int dt  = bid % 3;
    int h   = (bid / 3) % HH;
    int b   = bid / (3 * HH);
    int tid = threadIdx.x;

    __shared__ float T[256 * 17];

    // yi = h + dy corresponds to y = h + dy - 3  (dy = 0..6)
    const float* Hbase = Hws + (((size_t)b * YROWS + h) * CW + dt * 16) * WW + tid;
    #pragma unroll
    for (int dl = 0; dl < 16; ++dl) {
        float s = 0.f;
        #pragma unroll
        for (int dy = 0; dy < 2*VR + 1; ++dy)
            s += Hbase[((size_t)dy * CW + dl) * WW];   // coalesced in w (=tid)
        T[tid * 17 + dl] = s;
    }
    __syncthreads();

    float* ob = out + ((size_t)(b * HH + h) * WW) * CW + dt * 16;
    for (int i = tid; i < 256 * 16; i += 256) {
        int w2 = i >> 4, dl = i & 15;
        ob[w2 * CW + dl] = T[w2 * 17 + dl];   // d-contiguous 64B runs
    }
}

extern "C" void kernel_launch(void* const* d_in, const int* in_sizes, int n_in,
                              void* d_out, int out_size, void* d_ws, size_t ws_size,
                              hipStream_t stream) {
    const float* L = (const float*)d_in[0];
    const float* R = (const float*)d_in[1];
    float* out = (float*)d_out;
    float* Hws = (float*)d_ws;   // needs BB*YROWS*CW*WW*4 = ~13.2 MB

    ssd_hraw_kernel<<<dim3(BB * YROWS * 4), 256, 0, stream>>>(L, R, Hws);
    vsum_store_kernel<<<dim3(BB * HH * 3), 256, 0, stream>>>(Hws, out);
}

// Round 4
// 31.062 us; speedup vs baseline: 1.5361x; 1.4685x over previous
//
#include <hip/hip_runtime.h>

#define CW 48
#define HR 3
#define VR 3
#define BB 2
#define CC 16
#define HH 128
#define WW 256

#define LW 312      // Lsh stride: idx = x+3, L valid 3..258, read up to 311
#define RW2 264     // Rsh stride: idx = x+3, valid 3..258
#define SW 264      // Ssh stride (xi 0..263, only 0..261 used downstream)
#define FWD (WW*CW) // 12288 floats per (b,h) plane

// ------------- Kernel A: one block per (b,y) row; all 48 disparities -------------
// computes Hws[b][y][w][d] = horizontal 7-tap of ssd_raw(y, x, d)
__global__ __launch_bounds__(256) void ssd_hraw(
    const float* __restrict__ Lg, const float* __restrict__ Rg,
    float* __restrict__ Hws)
{
    const int bid = blockIdx.x;
    const int y   = bid % HH;
    const int b   = bid / HH;
    const int tid = threadIdx.x;

    __shared__ float Lsh[CC * LW];
    __shared__ float Rsh[CC * RW2];
    __shared__ float Ssh[CW * SW];
    __shared__ float el[LW];
    __shared__ float er[RW2];

    // zero the pad regions only (valid cols overwritten below)
    for (int i = tid; i < CC * 56; i += 256) {      // Lsh: idx 0..2 and 259..311
        int c = i / 56, j = i % 56;
        int idx = (j < 3) ? j : (256 + j);
        Lsh[c * LW + idx] = 0.f;
    }
    for (int i = tid; i < CC * 8; i += 256) {       // Rsh: idx 0..2 and 259..263
        int c = i / 8, j = i % 8;
        int idx = (j < 3) ? j : (256 + j);
        Rsh[c * RW2 + idx] = 0.f;
    }

    // stage one image row (all 16 channels), coalesced
    const size_t ib = ((size_t)b * CC) * (HH * WW) + (size_t)y * WW + tid;
    #pragma unroll
    for (int c = 0; c < CC; ++c) {
        Lsh[c * LW  + HR + tid] = Lg[ib + (size_t)c * (HH * WW)];
        Rsh[c * RW2 + HR + tid] = Rg[ib + (size_t)c * (HH * WW)];
    }
    __syncthreads();

    // el(idx) = sum_c L^2, er(idx) = sum_c R^2  (zero-padded via Lsh/Rsh pads)
    for (int i = tid; i < LW; i += 256) {
        float s = 0.f;
        #pragma unroll
        for (int c = 0; c < CC; ++c) { float v = Lsh[c * LW + i]; s = fmaf(v, v, s); }
        el[i] = s;
    }
    for (int i = tid; i < RW2; i += 256) {
        float s = 0.f;
        #pragma unroll
        for (int c = 0; c < CC; ++c) { float v = Rsh[c * RW2 + i]; s = fmaf(v, v, s); }
        er[i] = s;
    }
    __syncthreads();

    // cross-correlation cc(xi, d) with XV=4 xi-blocking, 12 d per unit.
    // units u = q*66 + xb : q in 0..3 (d0 = 12q), xb in 0..65 (xi0 = 4*xb)
    for (int u = tid; u < 264; u += 256) {
        int q   = u / 66;
        int xi0 = (u - q * 66) * 4;
        int d0  = q * 12;

        float acc[12][4];
        #pragma unroll
        for (int dd = 0; dd < 12; ++dd)
            #pragma unroll
            for (int xv = 0; xv < 4; ++xv) acc[dd][xv] = 0.f;

        #pragma unroll
        for (int c = 0; c < CC; ++c) {
            const float4 rv = *(const float4*)&Rsh[c * RW2 + xi0];
            const float rr[4] = {rv.x, rv.y, rv.z, rv.w};
            float lv[16];
            #pragma unroll
            for (int k = 0; k < 4; ++k)
                *(float4*)&lv[4 * k] = *(const float4*)&Lsh[c * LW + xi0 + d0 + 4 * k];
            #pragma unroll
            for (int dd = 0; dd < 12; ++dd)
                #pragma unroll
                for (int xv = 0; xv < 4; ++xv)
                    acc[dd][xv] = fmaf(lv[dd + xv], rr[xv], acc[dd][xv]);
        }

        // ssd = el(xi+d) + er(xi) - 2*cc
        float elv[16];
        #pragma unroll
        for (int k = 0; k < 4; ++k)
            *(float4*)&elv[4 * k] = *(const float4*)&el[xi0 + d0 + 4 * k];
        const float4 e4 = *(const float4*)&er[xi0];
        const float err4[4] = {e4.x, e4.y, e4.z, e4.w};
        #pragma unroll
        for (int dd = 0; dd < 12; ++dd) {
            float4 o;
            o.x = elv[dd + 0] + err4[0] - 2.f * acc[dd][0];
            o.y = elv[dd + 1] + err4[1] - 2.f * acc[dd][1];
            o.z = elv[dd + 2] + err4[2] - 2.f * acc[dd][2];
            o.w = elv[dd + 3] + err4[3] - 2.f * acc[dd][3];
            *(float4*)&Ssh[(d0 + dd) * SW + xi0] = o;
        }
    }
    __syncthreads();

    // horizontal 7-tap + d-contiguous store. 256 units: q = tid>>6, w0 = (tid&63)*4
    {
        const int q  = tid >> 6;
        const int w0 = (tid & 63) * 4;
        const int d0 = q * 12;
        float hs[12][4];
        #pragma unroll
        for (int dd = 0; dd < 12; ++dd) {
            const float* row = &Ssh[(d0 + dd) * SW];
            const float4 a = *(const float4*)&row[w0];
            const float4 bv = *(const float4*)&row[w0 + 4];
            const float2 cv = *(const float2*)&row[w0 + 8];
            float p = a.x + a.y + a.z + a.w + bv.x + bv.y + bv.z;
            hs[dd][0] = p;
            p += bv.w - a.x; hs[dd][1] = p;
            p += cv.x - a.y; hs[dd][2] = p;
            p += cv.y - a.z; hs[dd][3] = p;
        }
        float* H = Hws + (size_t)(b * HH + y) * FWD;
        #pragma unroll
        for (int xv = 0; xv < 4; ++xv) {
            float4 v0 = {hs[0][xv], hs[1][xv], hs[2][xv],  hs[3][xv]};
            float4 v1 = {hs[4][xv], hs[5][xv], hs[6][xv],  hs[7][xv]};
            float4 v2 = {hs[8][xv], hs[9][xv], hs[10][xv], hs[11][xv]};
            float* p = &H[(w0 + xv) * CW + d0];
            *(float4*)&p[0] = v0;
            *(float4*)&p[4] = v1;
            *(float4*)&p[8] = v2;
        }
    }
}

// ------------- Kernel B: vertical 7-tap running sum, fully coalesced -------------
#define HSEG 16
__global__ __launch_bounds__(256) void vbox(
    const float* __restrict__ Hws, float* __restrict__ out)
{
    const int bid = blockIdx.x;               // grid: b * (HH/HSEG) * 48
    const int fb  = bid % 48;
    const int hs  = (bid / 48) % (HH / HSEG);
    const int b   = bid / (48 * (HH / HSEG));
    const int f   = fb * 256 + threadIdx.x;   // f = w*48 + d
    const int h0  = hs * HSEG;

    const float* H = Hws + (size_t)b * HH * FWD + f;
    float*       O = out + (size_t)b * HH * FWD + f;

    float s = 0.f;
    #pragma unroll
    for (int k = 0; k < 6; ++k) {             // yy = h0-3 .. h0+2
        int yy = h0 - 3 + k;
        if (yy >= 0) s += H[(size_t)yy * FWD];
    }
    #pragma unroll
    for (int h0i = 0; h0i < HSEG; ++h0i) {
        int h = h0 + h0i;
        if (h + 3 < HH) s += H[(size_t)(h + 3) * FWD];
        O[(size_t)h * FWD] = s;
        if (h - 3 >= 0) s -= H[(size_t)(h - 3) * FWD];
    }
}

extern "C" void kernel_launch(void* const* d_in, const int* in_sizes, int n_in,
                              void* d_out, int out_size, void* d_ws, size_t ws_size,
                              hipStream_t stream) {
    const float* L = (const float*)d_in[0];
    const float* R = (const float*)d_in[1];
    float* out = (float*)d_out;
    float* Hws = (float*)d_ws;   // BB*HH*WW*CW*4 = 12.6 MB

    ssd_hraw<<<dim3(BB * HH), 256, 0, stream>>>(L, R, Hws);
    vbox<<<dim3(BB * (HH / HSEG) * 48), 256, 0, stream>>>(Hws, out);
}